// Round 15
// baseline (547.012 us; speedup 1.0000x reference)
//
#include <hip/hip_runtime.h>
#include <hip/hip_bf16.h>
#include <math.h>

#define C 8
#define K 128
#define S 64
#define L 2048
#define NB 64
#define W (L - S + 1)   // 1985
#define TW 128
#define NTW 16
#define XCS 208         // xcop stride shorts: 104 dw = 8 banks mod 32; 416 B (16B-aligned)
#define XFS 200         // fp32 x scratch stride (192 data + 8 zero pad)

typedef __attribute__((ext_vector_type(8))) short bf16x8;
typedef __attribute__((ext_vector_type(4))) float f32x4;

__device__ __forceinline__ unsigned short f2bf(float f) {
  unsigned int u = __float_as_uint(f);
  u += 0x7FFFu + ((u >> 16) & 1u);   // RNE
  return (unsigned short)(u >> 16);
}

// packed f32x2 -> bf16x2 (v_cvt_pk_bf16_f32 on gfx950)
__device__ __forceinline__ unsigned int pkbf(float a, float b) {
  __hip_bfloat162 h = __float22bfloat162_rn(make_float2(a, b));
  return *reinterpret_cast<unsigned int*>(&h);
}

// full-wave ONLY (R8 lesson: lane-predicated global_load_lds explodes traffic)
__device__ __forceinline__ void gll16(const void* g, void* l) {
  __builtin_amdgcn_global_load_lds((const __attribute__((address_space(1))) void*)g,
                                   (__attribute__((address_space(3))) void*)l, 16, 0, 0);
}

// prep: z-normalize shapelets -> bf16 * (-2) in B-fragment order, 16 KB per
// channel contiguous; init out to +inf. sum(z^2) == 64 exactly -> no sqs.
__global__ __launch_bounds__(256) void prep_kernel(const float* __restrict__ sh,
                                                   unsigned short* __restrict__ shzB,
                                                   float* __restrict__ out) {
  int tid = blockIdx.x * 256 + threadIdx.x;
  if (tid < NB * K) out[tid] = __int_as_float(0x7F800000);
  int gid = blockIdx.x * 4 + (threadIdx.x >> 6);  // c*K + k
  int lane = threadIdx.x & 63;                    // = s
  float v = sh[(size_t)gid * S + lane];
  float s1 = v, s2 = v * v;
#pragma unroll
  for (int off = 32; off > 0; off >>= 1) {
    s1 += __shfl_down(s1, off);
    s2 += __shfl_down(s2, off);
  }
  s1 = __shfl(s1, 0);
  s2 = __shfl(s2, 0);
  float mu = s1 * (1.0f / S);
  float sd = sqrtf(fmaxf(s2 * (1.0f / S) - mu * mu, 0.0f));
  float z = (v - mu) / sd;
  int c = gid >> 7, k = gid & (K - 1), s = lane;
  // B-frag layout: [c][k>>4][s>>5][lane'=((s>>3)&3)*16+(k&15)][s&7]
  int idx = c * 8192 + ((k >> 4) * 2 + (s >> 5)) * 512 +
            ((((s >> 3) & 3) * 16 + (k & 15)) * 8) + (s & 7);
  shzB[idx] = f2bf(-2.0f * z);   // bake the -2 of d2 = (sqx + 64) - 2*cross
}

// main: block = 128w x 128k, 512 threads = 8 waves, wave tile 64w x 32k
// (8 LDS-bytes per output-channel -- the measured binder at R13).
// R5's proven no-spill loop skeleton: double-buffered B, ONE barrier per
// channel at iteration end; prefetch at iteration top into the other buffer;
// bfr loaded inside the compute region (only dsum crosses barriers).
__global__ __launch_bounds__(512, 4) void main_kernel(const float* __restrict__ x,
                                                      const unsigned short* __restrict__ shzB,
                                                      int* __restrict__ out) {
  __shared__ __align__(16) unsigned short bbuf[2][8192];   // 32 KB B dbuf (16 KB = full K)
  __shared__ __align__(16) unsigned short xcop[C][8][XCS]; // 26 KB: 8 shifted copies
  __shared__ __align__(16) float sqx[C][TW];               // 4 KB (pre-biased +64)

  const int t = threadIdx.x;
  const int lane = t & 63;
  const int wave = t >> 6;     // 0..7
  const int wgrp = wave & 1;   // w-offset 64
  const int kgrp = wave >> 1;  // 0..3 : k-offset 32*kgrp
  const int col = lane & 15;
  const int quad = lane >> 4;
  const int n = blockIdx.y;
  const int w0 = blockIdx.x * TW;
  const float* xn = x + (size_t)n * C * L;

  // ---- stage fp32 x segment into bbuf-as-scratch (wave c, float4/lane) ----
  float* xf = (float*)&bbuf[0][0];  // 8 ch x XFS floats = 6.4 KB
  {
    const int c = wave;
    const int e = lane * 4;
    float4 v; v.x = v.y = v.z = v.w = 0.0f;
    if (lane < 48) {
      int g = w0 + e;
      if (g + 3 < L) {
        v = *(const float4*)(xn + c * L + g);
      } else {  // last w-tile tail; feeds masked windows only
        v.x = (g + 0 < L) ? xn[c * L + g + 0] : 0.0f;
        v.y = (g + 1 < L) ? xn[c * L + g + 1] : 0.0f;
        v.z = (g + 2 < L) ? xn[c * L + g + 2] : 0.0f;
        v.w = (g + 3 < L) ? xn[c * L + g + 3] : 0.0f;
      }
    }
    if (lane < 50) *(float4*)&xf[c * XFS + e] = v;   // lanes 48,49 zero-pad tail
  }
  __syncthreads();

  // ---- build 8 shifted bf16 copies (wave c; r=lane>>3; 12 dwords/lane) ----
  {
    const int cb = wave;
    const int rb = lane >> 3;         // 0..7
    const int c8 = lane & 7;
    const float* xr = xf + cb * XFS;
#pragma unroll
    for (int j = 0; j < 12; ++j) {
      int i = (c8 + j * 8) * 2;       // 0..190 even
      *(unsigned int*)&xcop[cb][rb][i] = pkbf(xr[i + rb], xr[i + rb + 1]);
    }
  }
  // ---- sliding-window fp32 sqx (+64 bias = sum(z^2)): wave c, 2 w/lane ----
  {
    const int c = wave, wl = lane * 2;
    const float* xr = xf + c * XFS;
    float p0 = 0.f, p1 = 0.f, p2 = 0.f, p3 = 0.f;
#pragma unroll
    for (int si = 0; si < S; si += 4) {
      float v0 = xr[wl + si], v1 = xr[wl + si + 1], v2 = xr[wl + si + 2], v3 = xr[wl + si + 3];
      p0 = fmaf(v0, v0, p0); p1 = fmaf(v1, v1, p1);
      p2 = fmaf(v2, v2, p2); p3 = fmaf(v3, v3, p3);
    }
    float s0 = 64.0f + (p0 + p1) + (p2 + p3);
    sqx[c][wl] = s0;
    float a = xr[wl + S], b = xr[wl];
    sqx[c][wl + 1] = s0 + a * a - b * b;
  }
  __syncthreads();  // xf dead -> bbuf[0] free for B

  // ---- B channel 0 into bbuf[0]: 16 KB via 2 full-wave gll16 per thread ----
#pragma unroll
  for (int i = 0; i < 2; ++i)
    gll16(shzB + i * 4096 + t * 8, &bbuf[0][i * 4096 + wave * 512]);
  __syncthreads();  // B[0] landed (vmcnt drained)

  const f32x4 z4 = {0.0f, 0.0f, 0.0f, 0.0f};
  f32x4 dsum[4][2];
#pragma unroll
  for (int a = 0; a < 4; ++a)
#pragma unroll
    for (int b = 0; b < 2; ++b) dsum[a][b] = z4;

  const int r8 = col & 7;
  const int abase = wgrp * 64 + (col - r8) + quad * 8;  // multiple of 8 -> b128 aligned

  for (int c = 0; c < C; ++c) {
    // prefetch next channel into the other buffer (read buffer untouched)
    if (c + 1 < C) {
#pragma unroll
      for (int i = 0; i < 2; ++i)
        gll16(shzB + (c + 1) * 8192 + i * 4096 + t * 8,
              &bbuf[(c + 1) & 1][i * 4096 + wave * 512]);
    }
    const unsigned short* bb = bbuf[c & 1];
    const unsigned short* xc = &xcop[c][r8][0];

    // acc init = bare ds_read of pre-biased sqx
    f32x4 acc[4][2];
#pragma unroll
    for (int wt = 0; wt < 4; ++wt) {
      f32x4 sx = *(const f32x4*)&sqx[c][wgrp * 64 + wt * 16 + quad * 4];
      acc[wt][0] = sx;
      acc[wt][1] = sx;
    }
#pragma unroll
    for (int ks = 0; ks < 2; ++ks) {
      bf16x8 b0 = *(const bf16x8*)(bb + ((kgrp * 2 + 0) * 2 + ks) * 512 + lane * 8);
      bf16x8 b1 = *(const bf16x8*)(bb + ((kgrp * 2 + 1) * 2 + ks) * 512 + lane * 8);
#pragma unroll
      for (int wt = 0; wt < 4; ++wt) {
        bf16x8 af = *(const bf16x8*)(xc + abase + wt * 16 + ks * 32);  // one b128
        acc[wt][0] = __builtin_amdgcn_mfma_f32_16x16x32_bf16(af, b0, acc[wt][0], 0, 0, 0);
        acc[wt][1] = __builtin_amdgcn_mfma_f32_16x16x32_bf16(af, b1, acc[wt][1], 0, 0, 0);
      }
    }
    // epilogue: dsum += v_sqrt(d2)
#pragma unroll
    for (int wt = 0; wt < 4; ++wt)
#pragma unroll
      for (int kt = 0; kt < 2; ++kt)
#pragma unroll
        for (int i = 0; i < 4; ++i)
          dsum[wt][kt][i] += __builtin_amdgcn_sqrtf(fmaxf(acc[wt][kt][i], 0.0f));

    __syncthreads();  // prefetch landed + all waves done reading bb
  }

  // min over w (regs -> quad shuffles), one atomicMin per k
  const float INF = __int_as_float(0x7F800000);
  int wbase = w0 + wgrp * 64;
#pragma unroll
  for (int kt = 0; kt < 2; ++kt) {
    float mv = INF;
#pragma unroll
    for (int wt = 0; wt < 4; ++wt)
#pragma unroll
      for (int i = 0; i < 4; ++i) {
        int w = wbase + wt * 16 + quad * 4 + i;
        mv = (w < W) ? fminf(mv, dsum[wt][kt][i]) : mv;
      }
    mv = fminf(mv, __shfl_xor(mv, 16));
    mv = fminf(mv, __shfl_xor(mv, 32));
    if (quad == 0)
      atomicMin(&out[n * K + kgrp * 32 + kt * 16 + col], __float_as_int(mv));
  }
}

extern "C" void kernel_launch(void* const* d_in, const int* in_sizes, int n_in,
                              void* d_out, int out_size, void* d_ws, size_t ws_size,
                              hipStream_t stream) {
  const float* x = (const float*)d_in[0];    // (64, 8, 2048) fp32
  const float* sh = (const float*)d_in[1];   // (8, 128, 64) fp32
  float* out = (float*)d_out;                // (64, 1, 128) fp32
  unsigned short* shzB = (unsigned short*)d_ws;  // 128 KB bf16 B-frag layout (scaled -2)

  prep_kernel<<<256, 256, 0, stream>>>(sh, shzB, out);
  main_kernel<<<dim3(NTW, NB), 512, 0, stream>>>(x, shzB, (int*)out);
}

// Round 16
// 97.124 us; speedup vs baseline: 5.6321x; 5.6321x over previous
//
#include <hip/hip_runtime.h>
#include <hip/hip_bf16.h>
#include <math.h>

#define C 8
#define K 128
#define S 64
#define L 2048
#define NB 64
#define W (L - S + 1)   // 1985
#define TW 128
#define NTW 16
#define NKB 2           // K split across 2 blocks (64 k each)
#define XCS 208         // xcop stride shorts: 104 dw = 8 banks mod 32 -> conflict-free b128
#define XFS 200         // fp32 x scratch stride (192 data + 8 zero pad)

typedef __attribute__((ext_vector_type(8))) short bf16x8;
typedef __attribute__((ext_vector_type(4))) float f32x4;

__device__ __forceinline__ unsigned short f2bf(float f) {
  unsigned int u = __float_as_uint(f);
  u += 0x7FFFu + ((u >> 16) & 1u);   // RNE
  return (unsigned short)(u >> 16);
}

// packed f32x2 -> bf16x2 (v_cvt_pk_bf16_f32 on gfx950)
__device__ __forceinline__ unsigned int pkbf(float a, float b) {
  __hip_bfloat162 h = __float22bfloat162_rn(make_float2(a, b));
  return *reinterpret_cast<unsigned int*>(&h);
}

// full-wave ONLY (R8 lesson: lane-predicated global_load_lds explodes traffic)
__device__ __forceinline__ void gll16(const void* g, void* l) {
  __builtin_amdgcn_global_load_lds((const __attribute__((address_space(1))) void*)g,
                                   (__attribute__((address_space(3))) void*)l, 16, 0, 0);
}

// prep: z-normalize shapelets -> bf16 * (-2), B-fragment order grouped by kblk
// (8 KB contiguous per (kblk, c)); init out to +inf. sum(z^2)==64 -> no sqs.
__global__ __launch_bounds__(256) void prep_kernel(const float* __restrict__ sh,
                                                   unsigned short* __restrict__ shzB,
                                                   float* __restrict__ out) {
  int tid = blockIdx.x * 256 + threadIdx.x;
  if (tid < NB * K) out[tid] = __int_as_float(0x7F800000);
  int gid = blockIdx.x * 4 + (threadIdx.x >> 6);  // c*K + k
  int lane = threadIdx.x & 63;                    // = s
  float v = sh[(size_t)gid * S + lane];
  float s1 = v, s2 = v * v;
#pragma unroll
  for (int off = 32; off > 0; off >>= 1) {
    s1 += __shfl_down(s1, off);
    s2 += __shfl_down(s2, off);
  }
  s1 = __shfl(s1, 0);
  s2 = __shfl(s2, 0);
  float mu = s1 * (1.0f / S);
  float sd = sqrtf(fmaxf(s2 * (1.0f / S) - mu * mu, 0.0f));
  float z = (v - mu) / sd;
  int c = gid >> 7, k = gid & (K - 1), s = lane;
  // layout: [k>>6][c][((k>>4)&3)*2 + (s>>5)][lane'=((s>>3)&3)*16+(k&15)][s&7]
  int idx = (k >> 6) * 32768 + c * 4096 + ((((k >> 4) & 3) * 2) + (s >> 5)) * 512 +
            ((((s >> 3) & 3) * 16 + (k & 15)) * 8) + (s & 7);
  shzB[idx] = f2bf(-2.0f * z);   // bake the -2 of d2 = (sqx + 64) - 2*cross
}

// main: R13's shape (block 128w x 64k, 8 waves of 64w x 16k, VGPR-lean) but
// B held in REGISTERS for the whole kernel (16 bf16x8 = 64 VGPRs, staged in
// 4 startup rounds through a 16 KB LDS bounce). The channel loop has ZERO
// barriers / ZERO global ops: pure ds_read(A,sqx) -> MFMA -> sqrt, fully
// unrolled (8 independent channel chains). R13's 2-barriers-per-channel
// drain idle (~28% of runtime) is deleted.
__global__ __launch_bounds__(512, 2) void main_kernel(const float* __restrict__ x,
                                                      const unsigned short* __restrict__ shzB,
                                                      int* __restrict__ out) {
  __shared__ __align__(16) unsigned short bbuf[8192];      // 16 KB bounce (xf scratch, then B)
  __shared__ __align__(16) unsigned short xcop[C][8][XCS]; // 26 KB: 8 shifted copies
  __shared__ __align__(16) float sqx[C][TW];               // 4 KB (pre-biased +64)

  const int t = threadIdx.x;
  const int lane = t & 63;
  const int wave = t >> 6;     // 0..7
  const int wgrp = wave & 1;   // w-offset 64
  const int kgrp = wave >> 1;  // 0..3 : k-offset 16*kgrp
  const int col = lane & 15;
  const int quad = lane >> 4;
  const int n = blockIdx.z;
  const int kblk = blockIdx.y;
  const int w0 = blockIdx.x * TW;
  const float* xn = x + (size_t)n * C * L;
  const unsigned short* bsrc = shzB + kblk * 32768;

  // ---- stage fp32 x segment into bbuf-as-scratch (wave c, float4/lane) ----
  float* xf = (float*)bbuf;  // 8 ch x XFS floats = 6.4 KB <= 16 KB
  {
    const int c = wave;
    const int e = lane * 4;
    float4 v; v.x = v.y = v.z = v.w = 0.0f;
    if (lane < 48) {
      int g = w0 + e;
      if (g + 3 < L) {
        v = *(const float4*)(xn + c * L + g);
      } else {  // last w-tile tail; feeds masked windows only
        v.x = (g + 0 < L) ? xn[c * L + g + 0] : 0.0f;
        v.y = (g + 1 < L) ? xn[c * L + g + 1] : 0.0f;
        v.z = (g + 2 < L) ? xn[c * L + g + 2] : 0.0f;
        v.w = (g + 3 < L) ? xn[c * L + g + 3] : 0.0f;
      }
    }
    if (lane < 50) *(float4*)&xf[c * XFS + e] = v;   // lanes 48,49 zero-pad tail
  }
  __syncthreads();

  // ---- build 8 shifted bf16 copies (wave c; r=lane>>3; 12 dwords/lane) ----
  {
    const int cb = wave;
    const int rb = lane >> 3;         // 0..7
    const int c8 = lane & 7;
    const float* xr = xf + cb * XFS;
#pragma unroll
    for (int j = 0; j < 12; ++j) {
      int i = (c8 + j * 8) * 2;       // 0..190 even
      *(unsigned int*)&xcop[cb][rb][i] = pkbf(xr[i + rb], xr[i + rb + 1]);
    }
  }
  // ---- sliding-window fp32 sqx (+64 bias = sum(z^2)): wave c, 2 w/lane ----
  {
    const int c = wave, wl = lane * 2;
    const float* xr = xf + c * XFS;
    float p0 = 0.f, p1 = 0.f, p2 = 0.f, p3 = 0.f;
#pragma unroll
    for (int si = 0; si < S; si += 4) {
      float v0 = xr[wl + si], v1 = xr[wl + si + 1], v2 = xr[wl + si + 2], v3 = xr[wl + si + 3];
      p0 = fmaf(v0, v0, p0); p1 = fmaf(v1, v1, p1);
      p2 = fmaf(v2, v2, p2); p3 = fmaf(v3, v3, p3);
    }
    float s0 = 64.0f + (p0 + p1) + (p2 + p3);
    sqx[c][wl] = s0;
    float a = xr[wl + S], b = xr[wl];
    sqx[c][wl + 1] = s0 + a * a - b * b;
  }
  __syncthreads();  // xf dead -> bbuf free for B staging

  // ---- stage ALL B into registers: 4 rounds x 2 channels through bbuf ----
  bf16x8 breg[16];  // [c*2 + ks], this wave's kgrp slice; 64 VGPRs, persistent
#pragma unroll
  for (int r = 0; r < 4; ++r) {
#pragma unroll
    for (int i = 0; i < 2; ++i)  // channel 2r+i -> bbuf[i*4096..]
      gll16(bsrc + (2 * r + i) * 4096 + t * 8, &bbuf[i * 4096 + wave * 512]);
    __syncthreads();  // gll16 landed (vmcnt drained by barrier)
#pragma unroll
    for (int i = 0; i < 2; ++i)
#pragma unroll
      for (int ks = 0; ks < 2; ++ks)
        breg[(2 * r + i) * 2 + ks] =
            *(const bf16x8*)(&bbuf[i * 4096 + (kgrp * 2 + ks) * 512 + lane * 8]);
    if (r < 3) __syncthreads();  // all waves read before next overwrite
  }

  const f32x4 z4 = {0.0f, 0.0f, 0.0f, 0.0f};
  f32x4 dsum[4];
#pragma unroll
  for (int a = 0; a < 4; ++a) dsum[a] = z4;

  const int r8 = col & 7;
  const int abase = wgrp * 64 + (col - r8) + quad * 8;  // multiple of 8 -> b128 aligned

  // ================= channel loop: ZERO barriers =================
#pragma unroll
  for (int c = 0; c < C; ++c) {
    f32x4 acc[4];
#pragma unroll
    for (int wt = 0; wt < 4; ++wt)   // acc init = bare ds_read of biased sqx
      acc[wt] = *(const f32x4*)&sqx[c][wgrp * 64 + wt * 16 + quad * 4];
    const unsigned short* xc = &xcop[c][r8][0];
#pragma unroll
    for (int wt = 0; wt < 4; ++wt) {
      bf16x8 a0 = *(const bf16x8*)(xc + abase + wt * 16);
      acc[wt] = __builtin_amdgcn_mfma_f32_16x16x32_bf16(a0, breg[c * 2 + 0], acc[wt], 0, 0, 0);
    }
#pragma unroll
    for (int wt = 0; wt < 4; ++wt) {
      bf16x8 a1 = *(const bf16x8*)(xc + abase + wt * 16 + 32);
      acc[wt] = __builtin_amdgcn_mfma_f32_16x16x32_bf16(a1, breg[c * 2 + 1], acc[wt], 0, 0, 0);
    }
#pragma unroll
    for (int wt = 0; wt < 4; ++wt)
#pragma unroll
      for (int i = 0; i < 4; ++i)
        dsum[wt][i] += __builtin_amdgcn_sqrtf(fmaxf(acc[wt][i], 0.0f));
  }

  // min over w (regs -> quad shuffles), one atomicMin per k
  const float INF = __int_as_float(0x7F800000);
  int wbase = w0 + wgrp * 64;
  float mv = INF;
#pragma unroll
  for (int wt = 0; wt < 4; ++wt)
#pragma unroll
    for (int i = 0; i < 4; ++i) {
      int w = wbase + wt * 16 + quad * 4 + i;
      mv = (w < W) ? fminf(mv, dsum[wt][i]) : mv;
    }
  mv = fminf(mv, __shfl_xor(mv, 16));
  mv = fminf(mv, __shfl_xor(mv, 32));
  if (quad == 0)
    atomicMin(&out[n * K + kblk * 64 + kgrp * 16 + col], __float_as_int(mv));
}

extern "C" void kernel_launch(void* const* d_in, const int* in_sizes, int n_in,
                              void* d_out, int out_size, void* d_ws, size_t ws_size,
                              hipStream_t stream) {
  const float* x = (const float*)d_in[0];    // (64, 8, 2048) fp32
  const float* sh = (const float*)d_in[1];   // (8, 128, 64) fp32
  float* out = (float*)d_out;                // (64, 1, 128) fp32
  unsigned short* shzB = (unsigned short*)d_ws;  // 128 KB bf16 B-frag layout (scaled -2)

  prep_kernel<<<256, 256, 0, stream>>>(sh, shzB, out);
  main_kernel<<<dim3(NTW, NKB, NB), 512, 0, stream>>>(x, shzB, (int*)out);
}

// Round 17
// 94.975 us; speedup vs baseline: 5.7595x; 1.0226x over previous
//
#include <hip/hip_runtime.h>
#include <hip/hip_bf16.h>
#include <math.h>

#define C 8
#define K 128
#define S 64
#define L 2048
#define NB 64
#define W (L - S + 1)   // 1985
#define TW 128
#define NTW 16
#define XCS 208         // xcop stride (shorts); mult of 4 -> 8B-aligned b64 reads
#define XFS 200         // fp32 x scratch stride (192 data + 8 zero pad)

typedef __attribute__((ext_vector_type(8))) short bf16x8;
typedef __attribute__((ext_vector_type(4))) short short4v;
typedef __attribute__((ext_vector_type(4))) float f32x4;
typedef __attribute__((ext_vector_type(16))) float f32x16;

__device__ __forceinline__ unsigned short f2bf(float f) {
  unsigned int u = __float_as_uint(f);
  u += 0x7FFFu + ((u >> 16) & 1u);   // RNE
  return (unsigned short)(u >> 16);
}

// packed f32x2 -> bf16x2 (v_cvt_pk_bf16_f32 on gfx950)
__device__ __forceinline__ unsigned int pkbf(float a, float b) {
  __hip_bfloat162 h = __float22bfloat162_rn(make_float2(a, b));
  return *reinterpret_cast<unsigned int*>(&h);
}

// full-wave ONLY (R8 lesson: lane-predicated global_load_lds explodes traffic)
__device__ __forceinline__ void gll16(const void* g, void* l) {
  __builtin_amdgcn_global_load_lds((const __attribute__((address_space(1))) void*)g,
                                   (__attribute__((address_space(3))) void*)l, 16, 0, 0);
}

// prep: z-normalize shapelets -> bf16 * (-2) in 32x32x16 B-fragment order
// (verified in R11, absmax 0.5); init out to +inf. sum(z^2)==64 -> no sqs.
__global__ __launch_bounds__(256) void prep_kernel(const float* __restrict__ sh,
                                                   unsigned short* __restrict__ shzB,
                                                   float* __restrict__ out) {
  int tid = blockIdx.x * 256 + threadIdx.x;
  if (tid < NB * K) out[tid] = __int_as_float(0x7F800000);
  int gid = blockIdx.x * 4 + (threadIdx.x >> 6);  // c*K + k
  int lane = threadIdx.x & 63;                    // = s
  float v = sh[(size_t)gid * S + lane];
  float s1 = v, s2 = v * v;
#pragma unroll
  for (int off = 32; off > 0; off >>= 1) {
    s1 += __shfl_down(s1, off);
    s2 += __shfl_down(s2, off);
  }
  s1 = __shfl(s1, 0);
  s2 = __shfl(s2, 0);
  float mu = s1 * (1.0f / S);
  float sd = sqrtf(fmaxf(s2 * (1.0f / S) - mu * mu, 0.0f));
  float z = (v - mu) / sd;
  int c = gid >> 7, k = gid & (K - 1), s = lane;
  int idx = c * 8192 + (k >> 5) * 2048 + (s >> 4) * 512 +
            ((((s >> 3) & 1) * 32 + (k & 31)) * 8) + (s & 7);
  shzB[idx] = f2bf(-2.0f * z);   // bake the -2 of d2 = (sqx + 64) - 2*cross
}

// main: R11's 64w x 64k wave tile (32x32x16 MFMA — the LDS-traffic-optimal
// shape: ~13 us LDS model vs R13's 36) with occupancy unclogged:
// no sqsl (sqx pre-biased +64), 4-copy xcop (13.3 KB) -> LDS 49.3 KB ->
// 3 blocks/CU = 12 waves/CU (R11 ran at 8). Structure otherwise R11-identical.
__global__ __launch_bounds__(256, 3) void main_kernel(const float* __restrict__ x,
                                                      const unsigned short* __restrict__ shzB,
                                                      int* __restrict__ out) {
  __shared__ __align__(16) unsigned short bbuf[2][8192];   // 32 KB B dbuf (16 KB = full K per ch)
  __shared__ __align__(16) unsigned short xcop[C][4][XCS]; // 13.3 KB: 4 shifted bf16 copies
  __shared__ __align__(16) float sqx[C][TW];               // 4 KB (pre-biased +64)

  const int t = threadIdx.x;
  const int lane = t & 63;
  const int wave = t >> 6;     // 0..3
  const int wgrp = wave & 1;   // w-offset 64
  const int kgrp = wave >> 1;  // k-offset 64
  const int m = lane & 31;     // MFMA row/col within 32
  const int h = lane >> 5;     // K-half
  const int n = blockIdx.y;
  const int w0 = blockIdx.x * TW;
  const float* xn = x + (size_t)n * C * L;

  // ---- stage fp32 x segment (8 ch x 192, stride 200, zero-padded) ----
  float* xf = (float*)&bbuf[0][0];  // 1600 floats, dies before B[0] load
#pragma unroll
  for (int j = 0; j < 7; ++j) {
    int s = j * 256 + t;
    if (s < C * XFS) {
      int c = s / XFS, e = s - c * XFS;
      int g = w0 + e;
      xf[s] = (e < 192 && g < L) ? xn[c * L + g] : 0.0f;
    }
  }
  __syncthreads();

  // ---- build 4 shifted bf16 copies: 8c x 4r x 96 dwords over 256 threads ----
#pragma unroll
  for (int j = 0; j < 12; ++j) {
    int idx = j * 256 + t;
    int c = idx / 384, rem = idx - c * 384;
    int r = rem / 96, i2 = rem - r * 96;
    int i = i2 * 2;
    *(unsigned int*)&xcop[c][r][i] = pkbf(xf[c * XFS + i + r], xf[c * XFS + i + r + 1]);
  }
  // ---- sliding-window fp32 sqx (+64 bias): thread -> (c, 4 consecutive w) ----
  {
    int c = t >> 5, wl = (t & 31) * 4;
    const float* xr = xf + c * XFS;
    float p0 = 0.f, p1 = 0.f, p2 = 0.f, p3 = 0.f;
#pragma unroll
    for (int si = 0; si < S; si += 4) {
      float v0 = xr[wl + si], v1 = xr[wl + si + 1], v2 = xr[wl + si + 2], v3 = xr[wl + si + 3];
      p0 = fmaf(v0, v0, p0); p1 = fmaf(v1, v1, p1);
      p2 = fmaf(v2, v2, p2); p3 = fmaf(v3, v3, p3);
    }
    float s0 = 64.0f + (p0 + p1) + (p2 + p3);
    sqx[c][wl] = s0;
#pragma unroll
    for (int q = 1; q < 4; ++q) {
      float a = xr[wl + S - 1 + q], b = xr[wl + q - 1];
      s0 += a * a - b * b;
      sqx[c][wl + q] = s0;
    }
  }
  __syncthreads();  // xf dead -> bbuf[0] free for B

  // ---- B channel 0 into bbuf[0]: 16 KB over 256 threads = 4 x 16B ----
#pragma unroll
  for (int i = 0; i < 4; ++i)
    gll16(shzB + i * 2048 + t * 8, &bbuf[0][i * 2048 + wave * 512]);

  f32x16 dsum[2][2];
#pragma unroll
  for (int a = 0; a < 2; ++a)
#pragma unroll
    for (int b = 0; b < 2; ++b)
#pragma unroll
      for (int e = 0; e < 16; ++e) dsum[a][b][e] = 0.0f;

  const int r4 = m & 3;

  for (int c = 0; c < C; ++c) {
    __syncthreads();  // B[c] ready in bbuf[c&1] (drains prefetch vmcnt)
    if (c + 1 < C) {  // prefetch next channel into the other buffer
#pragma unroll
      for (int i = 0; i < 4; ++i)
        gll16(shzB + (c + 1) * 8192 + i * 2048 + t * 8,
              &bbuf[(c + 1) & 1][i * 2048 + wave * 512]);
    }
    const unsigned short* bb = bbuf[c & 1];

    // B fragments for this channel: 2 ktiles x 4 ksteps (cached in regs)
    bf16x8 bfr[8];
#pragma unroll
    for (int kt = 0; kt < 2; ++kt)
#pragma unroll
      for (int ks = 0; ks < 4; ++ks)
        bfr[kt * 4 + ks] = *(const bf16x8*)(bb + (kgrp * 2 + kt) * 2048 + ks * 512 + lane * 8);

#pragma unroll
    for (int wsub = 0; wsub < 2; ++wsub) {
      const int wb = wgrp * 64 + wsub * 32;
      // sqx rows for this 32-row band: row = (e&3) + 8*(e>>2) + 4*h (pre-biased)
      f32x4 sxv[4];
#pragma unroll
      for (int g = 0; g < 4; ++g)
        sxv[g] = *(const f32x4*)&sqx[c][wb + 8 * g + 4 * h];
      // A fragments (4 ksteps, cached; 2 x b64 aligned reads each)
      const unsigned short* xc = &xcop[c][r4][0];
      bf16x8 af[4];
#pragma unroll
      for (int ks = 0; ks < 4; ++ks) {
        int base = wb + (m - r4) + ks * 16 + 8 * h;  // mult of 4 -> 8B aligned
        short4v lo = *(const short4v*)(xc + base);
        short4v hi = *(const short4v*)(xc + base + 4);
        af[ks] = __builtin_shufflevector(lo, hi, 0, 1, 2, 3, 4, 5, 6, 7);
      }
#pragma unroll
      for (int kt = 0; kt < 2; ++kt) {
        f32x16 acc;
#pragma unroll
        for (int g = 0; g < 4; ++g)
#pragma unroll
          for (int i = 0; i < 4; ++i) acc[g * 4 + i] = sxv[g][i];  // bare init, no adds
#pragma unroll
        for (int ks = 0; ks < 4; ++ks)
          acc = __builtin_amdgcn_mfma_f32_32x32x16_bf16(af[ks], bfr[kt * 4 + ks], acc, 0, 0, 0);
#pragma unroll
        for (int e = 0; e < 16; ++e)
          dsum[wsub][kt][e] += __builtin_amdgcn_sqrtf(fmaxf(acc[e], 0.0f));
      }
    }
  }

  // min over w (regs + h-pair shuffle), one atomicMin per k from lanes 0..31
  const float INF = __int_as_float(0x7F800000);
#pragma unroll
  for (int kt = 0; kt < 2; ++kt) {
    float mv = INF;
#pragma unroll
    for (int wsub = 0; wsub < 2; ++wsub)
#pragma unroll
      for (int e = 0; e < 16; ++e) {
        int w = w0 + wgrp * 64 + wsub * 32 + (e & 3) + 8 * (e >> 2) + 4 * h;
        mv = (w < W) ? fminf(mv, dsum[wsub][kt][e]) : mv;
      }
    mv = fminf(mv, __shfl_xor(mv, 32));
    if (h == 0)
      atomicMin(&out[n * K + kgrp * 64 + kt * 32 + m], __float_as_int(mv));
  }
}

extern "C" void kernel_launch(void* const* d_in, const int* in_sizes, int n_in,
                              void* d_out, int out_size, void* d_ws, size_t ws_size,
                              hipStream_t stream) {
  const float* x = (const float*)d_in[0];    // (64, 8, 2048) fp32
  const float* sh = (const float*)d_in[1];   // (8, 128, 64) fp32
  float* out = (float*)d_out;                // (64, 1, 128) fp32
  unsigned short* shzB = (unsigned short*)d_ws;  // 128 KB bf16 B-frag layout (scaled -2)

  prep_kernel<<<256, 256, 0, stream>>>(sh, shzB, out);
  main_kernel<<<dim3(NTW, NB), 256, 0, stream>>>(x, shzB, (int*)out);
}

// Round 18
// 91.409 us; speedup vs baseline: 5.9842x; 1.0390x over previous
//
#include <hip/hip_runtime.h>
#include <hip/hip_bf16.h>
#include <math.h>

#define C 8
#define K 128
#define S 64
#define L 2048
#define NB 64
#define W (L - S + 1)   // 1985
#define TW 128
#define NTW 16
#define NKB 2           // K split across 2 blocks (64 k each)
#define XCS 208         // xcop stride shorts: 104 dw = 8 banks mod 32 -> conflict-free b128
#define XFS 200         // fp32 x scratch stride (192 data + 8 zero pad)

typedef __attribute__((ext_vector_type(8))) short bf16x8;
typedef __attribute__((ext_vector_type(4))) float f32x4;

__device__ __forceinline__ unsigned short f2bf(float f) {
  unsigned int u = __float_as_uint(f);
  u += 0x7FFFu + ((u >> 16) & 1u);   // RNE
  return (unsigned short)(u >> 16);
}

// packed f32x2 -> bf16x2 (v_cvt_pk_bf16_f32 on gfx950)
__device__ __forceinline__ unsigned int pkbf(float a, float b) {
  __hip_bfloat162 h = __float22bfloat162_rn(make_float2(a, b));
  return *reinterpret_cast<unsigned int*>(&h);
}

// full-wave ONLY (R8 lesson: lane-predicated global_load_lds explodes traffic)
__device__ __forceinline__ void gll16(const void* g, void* l) {
  __builtin_amdgcn_global_load_lds((const __attribute__((address_space(1))) void*)g,
                                   (__attribute__((address_space(3))) void*)l, 16, 0, 0);
}

// prep: z-normalize shapelets -> bf16 * (-2), B-fragment order grouped by kblk
// (8 KB contiguous per (kblk, c)); init out to +inf. NOTE: sum(z^2) == S == 64
// exactly (population z-norm), so no per-k sqs is needed anywhere.
__global__ __launch_bounds__(256) void prep_kernel(const float* __restrict__ sh,
                                                   unsigned short* __restrict__ shzB,
                                                   float* __restrict__ out) {
  int tid = blockIdx.x * 256 + threadIdx.x;
  if (tid < NB * K) out[tid] = __int_as_float(0x7F800000);
  int gid = blockIdx.x * 4 + (threadIdx.x >> 6);  // c*K + k
  int lane = threadIdx.x & 63;                    // = s
  float v = sh[(size_t)gid * S + lane];
  float s1 = v, s2 = v * v;
#pragma unroll
  for (int off = 32; off > 0; off >>= 1) {
    s1 += __shfl_down(s1, off);
    s2 += __shfl_down(s2, off);
  }
  s1 = __shfl(s1, 0);
  s2 = __shfl(s2, 0);
  float mu = s1 * (1.0f / S);
  float sd = sqrtf(fmaxf(s2 * (1.0f / S) - mu * mu, 0.0f));
  float z = (v - mu) / sd;
  int c = gid >> 7, k = gid & (K - 1), s = lane;
  // layout: [k>>6][c][((k>>4)&3)*2 + (s>>5)][lane'=((s>>3)&3)*16+(k&15)][s&7]
  int idx = (k >> 6) * 32768 + c * 4096 + ((((k >> 4) & 3) * 2) + (s >> 5)) * 512 +
            ((((s >> 3) & 3) * 16 + (k & 15)) * 8) + (s & 7);
  shzB[idx] = f2bf(-2.0f * z);   // bake the -2 of d2 = (sqx + 64) - 2*cross
}

// main: block = 128w x 64k (kblk), 512 threads = 8 waves, wave tile 64w x 16k.
// LDS 38 KB -> 4 blocks/CU. Channel loop:
//   [READY] -> B ds_reads -> [DONE] -> prefetch B[c+1] -> acc(ds_read)+MFMA+epilogue
// acc init is a BARE ds_read of sqx (the +64 = sum(z^2) is pre-biased in).
// Best measured configuration of the session (42.6 us main, VGPR 36, no spill):
// six structural variants (occupancy 8->50%, LDS traffic 1.8M->1.05M instrs,
// barriers 16->0, two MFMA shapes) all landed 42-50 us -- the binder is the
// irreducible ds_read->MFMA->v_sqrt->add chain, not any staged resource.
__global__ __launch_bounds__(512, 4) void main_kernel(const float* __restrict__ x,
                                                      const unsigned short* __restrict__ shzB,
                                                      int* __restrict__ out) {
  __shared__ __align__(16) unsigned short bbuf[4096];      // 8 KB: B[c] for this kblk
  __shared__ __align__(16) unsigned short xcop[C][8][XCS]; // 26 KB: 8 shifted copies
  __shared__ __align__(16) float sqx[C][TW];               // 4 KB (pre-biased +64)

  const int t = threadIdx.x;
  const int lane = t & 63;
  const int wave = t >> 6;     // 0..7
  const int wgrp = wave & 1;   // w-offset 64
  const int kgrp = wave >> 1;  // 0..3 : k-offset 16*kgrp
  const int col = lane & 15;
  const int quad = lane >> 4;
  const int n = blockIdx.z;
  const int kblk = blockIdx.y;
  const int w0 = blockIdx.x * TW;
  const float* xn = x + (size_t)n * C * L;
  const unsigned short* bsrc = shzB + kblk * 32768;

  // ---- stage fp32 x segment into bbuf-as-scratch (wave c, float4/lane) ----
  float* xf = (float*)bbuf;  // 8 ch x XFS floats = 6.4 KB <= 8 KB
  {
    const int c = wave;
    const int e = lane * 4;
    float4 v; v.x = v.y = v.z = v.w = 0.0f;
    if (lane < 48) {
      int g = w0 + e;
      if (g + 3 < L) {
        v = *(const float4*)(xn + c * L + g);
      } else {  // last w-tile tail; feeds masked windows only
        v.x = (g + 0 < L) ? xn[c * L + g + 0] : 0.0f;
        v.y = (g + 1 < L) ? xn[c * L + g + 1] : 0.0f;
        v.z = (g + 2 < L) ? xn[c * L + g + 2] : 0.0f;
        v.w = (g + 3 < L) ? xn[c * L + g + 3] : 0.0f;
      }
    }
    if (lane < 50) *(float4*)&xf[c * XFS + e] = v;   // lanes 48,49 zero-pad tail
  }
  __syncthreads();

  // ---- build 8 shifted bf16 copies (wave c; r=lane>>3; 12 dwords/lane) ----
  {
    const int cb = wave;
    const int rb = lane >> 3;         // 0..7
    const int c8 = lane & 7;
    const float* xr = xf + cb * XFS;
#pragma unroll
    for (int j = 0; j < 12; ++j) {
      int i = (c8 + j * 8) * 2;       // 0..190 even
      *(unsigned int*)&xcop[cb][rb][i] = pkbf(xr[i + rb], xr[i + rb + 1]);
    }
  }
  // ---- sliding-window fp32 sqx (+64 bias = sum(z^2)): wave c, 2 w/lane ----
  {
    const int c = wave, wl = lane * 2;
    const float* xr = xf + c * XFS;
    float p0 = 0.f, p1 = 0.f, p2 = 0.f, p3 = 0.f;
#pragma unroll
    for (int si = 0; si < S; si += 4) {
      float v0 = xr[wl + si], v1 = xr[wl + si + 1], v2 = xr[wl + si + 2], v3 = xr[wl + si + 3];
      p0 = fmaf(v0, v0, p0); p1 = fmaf(v1, v1, p1);
      p2 = fmaf(v2, v2, p2); p3 = fmaf(v3, v3, p3);
    }
    float s0 = 64.0f + (p0 + p1) + (p2 + p3);
    sqx[c][wl] = s0;
    float a = xr[wl + S], b = xr[wl];
    sqx[c][wl + 1] = s0 + a * a - b * b;
  }
  __syncthreads();  // xf dead -> bbuf free for B

  // ---- B channel 0: one full-wave gll16 per thread (8 KB total) ----
  gll16(bsrc + t * 8, &bbuf[wave * 512]);

  const f32x4 z4 = {0.0f, 0.0f, 0.0f, 0.0f};
  f32x4 dsum[4];
#pragma unroll
  for (int a = 0; a < 4; ++a) dsum[a] = z4;

  const int r8 = col & 7;
  const int abase = wgrp * 64 + (col - r8) + quad * 8;  // multiple of 8 -> b128 aligned

  for (int c = 0; c < C; ++c) {
    __syncthreads();  // READY: bbuf holds B[c] (compiler drains vmcnt here)
    bf16x8 b0 = *(const bf16x8*)(&bbuf[(kgrp * 2 + 0) * 512 + lane * 8]);
    bf16x8 b1 = *(const bf16x8*)(&bbuf[(kgrp * 2 + 1) * 512 + lane * 8]);
    __syncthreads();  // DONE: all waves captured their B fragments

    if (c + 1 < C)    // prefetch lands during the compute below
      gll16(bsrc + (c + 1) * 4096 + t * 8, &bbuf[wave * 512]);

    // ---- barrier-free compute region: acc = ds_read(sqx) -> MFMA -> epilogue ----
    f32x4 acc[4];
#pragma unroll
    for (int wt = 0; wt < 4; ++wt)
      acc[wt] = *(const f32x4*)&sqx[c][wgrp * 64 + wt * 16 + quad * 4];
    const unsigned short* xc = &xcop[c][r8][0];
#pragma unroll
    for (int wt = 0; wt < 4; ++wt) {
      bf16x8 a0 = *(const bf16x8*)(xc + abase + wt * 16);
      acc[wt] = __builtin_amdgcn_mfma_f32_16x16x32_bf16(a0, b0, acc[wt], 0, 0, 0);
    }
#pragma unroll
    for (int wt = 0; wt < 4; ++wt) {
      bf16x8 a1 = *(const bf16x8*)(xc + abase + wt * 16 + 32);
      acc[wt] = __builtin_amdgcn_mfma_f32_16x16x32_bf16(a1, b1, acc[wt], 0, 0, 0);
    }
#pragma unroll
    for (int wt = 0; wt < 4; ++wt)
#pragma unroll
      for (int i = 0; i < 4; ++i)
        dsum[wt][i] += __builtin_amdgcn_sqrtf(fmaxf(acc[wt][i], 0.0f));
  }

  // min over w (regs -> quad shuffles), one atomicMin per k
  const float INF = __int_as_float(0x7F800000);
  int wbase = w0 + wgrp * 64;
  float mv = INF;
#pragma unroll
  for (int wt = 0; wt < 4; ++wt)
#pragma unroll
    for (int i = 0; i < 4; ++i) {
      int w = wbase + wt * 16 + quad * 4 + i;
      mv = (w < W) ? fminf(mv, dsum[wt][i]) : mv;
    }
  mv = fminf(mv, __shfl_xor(mv, 16));
  mv = fminf(mv, __shfl_xor(mv, 32));
  if (quad == 0)
    atomicMin(&out[n * K + kblk * 64 + kgrp * 16 + col], __float_as_int(mv));
}

extern "C" void kernel_launch(void* const* d_in, const int* in_sizes, int n_in,
                              void* d_out, int out_size, void* d_ws, size_t ws_size,
                              hipStream_t stream) {
  const float* x = (const float*)d_in[0];    // (64, 8, 2048) fp32
  const float* sh = (const float*)d_in[1];   // (8, 128, 64) fp32
  float* out = (float*)d_out;                // (64, 1, 128) fp32
  unsigned short* shzB = (unsigned short*)d_ws;  // 128 KB bf16 B-frag layout (scaled -2)

  prep_kernel<<<256, 256, 0, stream>>>(sh, shzB, out);
  main_kernel<<<dim3(NTW, NKB, NB), 512, 0, stream>>>(x, shzB, (int*)out);
}